// Round 10
// baseline (250.511 us; speedup 1.0000x reference)
//
#include <hip/hip_runtime.h>
#include <hip/hip_fp16.h>
#include <stdint.h>

#define M_TOTAL 16384
#define N_TOTAL 572
#define N_PAD   640
#define K_TOTAL 1024
#define D_TOTAL 1024

typedef _Float16 f16;
typedef __attribute__((ext_vector_type(4))) _Float16 f16x4;
typedef __attribute__((ext_vector_type(8))) _Float16 f16x8;
typedef __attribute__((ext_vector_type(4))) float f32x4;

// B granule array geometry (f16 elements)
#define B_PLANE 655360   // 32 kblk * 40 ct * 4 kseg * 16 fr * 8 e
#define B_KSTEP 20480    // 40*4*16*8 : stride per kblk

// ---------------------------------------------------------------------------
// conv_w_gran: W1 f32 [K,572] -> hi/lo f16 planes in MFMA-granule order:
// elem(p, k, n) at  p*B_PLANE + (((kblk*40 + ct)*4 + kseg)*16 + fr)*8 + e
// where kblk=k>>5, kseg=(k>>3)&3, e=k&7, ct=n>>4, fr=n&15.
// A wave's B-fragment load (ct, kblk, lane->(fq,fr)) is then a contiguous,
// coalesced 1KB global_load_dwordx4 from this L2-resident 2.6MB array.
// Cols 572..639 zero-filled.
// ---------------------------------------------------------------------------
__global__ __launch_bounds__(256) void conv_w_gran(const float* __restrict__ W,
                                                   f16* __restrict__ Bg) {
  const int idx = blockIdx.x * 256 + threadIdx.x;  // over 640*1024
  const int n = idx % N_PAD;
  const int k = idx / N_PAD;
  const float x = (n < N_TOTAL) ? W[(size_t)k * N_TOTAL + n] : 0.0f;
  const f16 h = (f16)x;
  const f16 l = (f16)(x - (float)h);
  const size_t off = ((((size_t)(k >> 5) * 40 + (n >> 4)) * 4 + ((k >> 3) & 3)) * 16
                      + (n & 15)) * 8 + (k & 7);
  Bg[off] = h;
  Bg[B_PLANE + off] = l;
}

// ---------------------------------------------------------------------------
// JAX threefry2x32, key(42) -> (0,42); partitionable random_bits (32-bit)
// ---------------------------------------------------------------------------
__device__ __forceinline__ float jax_gumbel(uint32_t idx) {
  const uint32_t ks0 = 0u;
  const uint32_t ks1 = 42u;
  const uint32_t ks2 = 0x1BD11BDAu ^ ks0 ^ ks1;
  uint32_t x0 = ks0;
  uint32_t x1 = idx + ks1;
#define TF_ROUND(r) { x0 += x1; x1 = (x1 << (r)) | (x1 >> (32 - (r))); x1 ^= x0; }
  TF_ROUND(13) TF_ROUND(15) TF_ROUND(26) TF_ROUND(6)
  x0 += ks1; x1 += ks2 + 1u;
  TF_ROUND(17) TF_ROUND(29) TF_ROUND(16) TF_ROUND(24)
  x0 += ks2; x1 += ks0 + 2u;
  TF_ROUND(13) TF_ROUND(15) TF_ROUND(26) TF_ROUND(6)
  x0 += ks0; x1 += ks1 + 3u;
  TF_ROUND(17) TF_ROUND(29) TF_ROUND(16) TF_ROUND(24)
  x0 += ks1; x1 += ks2 + 4u;
  TF_ROUND(13) TF_ROUND(15) TF_ROUND(26) TF_ROUND(6)
  x0 += ks2; x1 += ks0 + 5u;
#undef TF_ROUND
  const uint32_t bits = x0 ^ x1;
  union { uint32_t u; float f; } cvt;
  cvt.u = (bits >> 9) | 0x3F800000u;
  const float fl = cvt.f - 1.0f;
  const float TINY = 1.1754943508222875e-38f;
  const float u = fmaxf(TINY, fl * 1.0f + TINY);
  return -logf(-logf(u));
}

// ---------------------------------------------------------------------------
// fused_head: per 64-row block -- 3-pass split-f16 MFMA GEMM (full 640-col
// width) + softmax + gumbel argmax + W2 gather + relu + residual.
// 512 thr = 8 waves; wave w owns cols [w*80, w*80+80) for ALL 64 rows.
// acc[4][5]: rows rt*16+fq*4+r, cols w*80+ct*16+fr.
// A: f32 -> hi/lo f16 in-register, double-buffered granule LDS (8KB/buf),
//    ONE barrier per k-step. B: direct from granule-ordered global (L2-hot).
// ---------------------------------------------------------------------------
__global__ __launch_bounds__(512, 2) void fused_head(
    const float* __restrict__ A,
    const f16* __restrict__ Bgr,
    const float* __restrict__ b1,
    const float* __restrict__ W2,
    const float* __restrict__ b2,
    float* __restrict__ probs,
    float* __restrict__ out1) {
  __shared__ __align__(16) f16 AgF[2][2][2048];  // [dbuf][plane][gran*8] 16KB
  __shared__ float red[8][64];
  __shared__ float rowM[64];
  __shared__ float rowS[64];
  __shared__ float rowL[64];
  __shared__ float avalS[8][64];
  __shared__ int   acolS[8][64];
  __shared__ int   actS[64];

  const int t = threadIdx.x;
  const int lane = t & 63, wid = t >> 6;  // wid = col group 0..7
  const int fr = lane & 15, fq = lane >> 4;
  const int m0 = blockIdx.x * 64;

  // ---- A staging: thread t = (granule gi, half hf) ----
  const int gi = t >> 1, hf = t & 1;
  const int aRow = ((gi >> 6) << 4) | (gi & 15);
  const int aK = ((gi >> 4) & 3) * 8 + hf * 4;
  const float* aP = A + (size_t)(m0 + aRow) * K_TOTAL + aK;

  // ---- B fragment pointers (per lane, per ct, per plane) ----
  const f16* pBh[5];
  const f16* pBl[5];
#pragma unroll
  for (int ct = 0; ct < 5; ++ct) {
    const int ctg = wid * 5 + ct;
    const size_t off = (((size_t)ctg * 4 + fq) * 16 + fr) * 8;
    pBh[ct] = Bgr + off;
    pBl[ct] = Bgr + B_PLANE + off;
  }

  // ---- b1 / validity per ct ----
  float b1v[5];
  bool vld[5];
#pragma unroll
  for (int ct = 0; ct < 5; ++ct) {
    const int col = wid * 80 + ct * 16 + fr;
    vld[ct] = (col < N_TOTAL);
    b1v[ct] = vld[ct] ? b1[col] : 0.0f;
  }

  f32x4 acc[4][5] = {};

  float4 rA;
  auto LOADA = [&](int k0) { rA = *reinterpret_cast<const float4*>(aP + k0); };
  auto WRITEA = [&](int db) {
    const float xv[4] = {rA.x, rA.y, rA.z, rA.w};
    f16x4 hi, lo;
#pragma unroll
    for (int j = 0; j < 4; ++j) {
      const f16 h = (f16)xv[j];
      hi[j] = h;
      lo[j] = (f16)(xv[j] - (float)h);
    }
    *reinterpret_cast<f16x4*>(&AgF[db][0][gi * 8 + hf * 4]) = hi;
    *reinterpret_cast<f16x4*>(&AgF[db][1][gi * 8 + hf * 4]) = lo;
  };

  // ---- K loop: 32 steps, one barrier each ----
  LOADA(0);
  WRITEA(0);
  __syncthreads();
  int db = 0;
  for (int kb = 0; kb < 32; ++kb) {
    if (kb < 31) LOADA((kb + 1) * 32);  // HBM latency hidden under this step
    f16x8 ahh[4], alo[4];
#pragma unroll
    for (int rt = 0; rt < 4; ++rt) {
      ahh[rt] = *reinterpret_cast<const f16x8*>(&AgF[db][0][(rt * 64 + lane) * 8]);
      alo[rt] = *reinterpret_cast<const f16x8*>(&AgF[db][1][(rt * 64 + lane) * 8]);
    }
#pragma unroll
    for (int ct = 0; ct < 5; ++ct) {
      const f16x8 bh = *reinterpret_cast<const f16x8*>(pBh[ct] + (size_t)kb * B_KSTEP);
      const f16x8 bl = *reinterpret_cast<const f16x8*>(pBl[ct] + (size_t)kb * B_KSTEP);
#pragma unroll
      for (int rt = 0; rt < 4; ++rt) {
        acc[rt][ct] = __builtin_amdgcn_mfma_f32_16x16x32_f16(ahh[rt], bh, acc[rt][ct], 0, 0, 0);
        acc[rt][ct] = __builtin_amdgcn_mfma_f32_16x16x32_f16(ahh[rt], bl, acc[rt][ct], 0, 0, 0);
        acc[rt][ct] = __builtin_amdgcn_mfma_f32_16x16x32_f16(alo[rt], bh, acc[rt][ct], 0, 0, 0);
      }
    }
    if (kb < 31) WRITEA(db ^ 1);  // other buffer: safe while db is read
    __syncthreads();              // db^1 complete; db reads complete
    db ^= 1;
  }

  const float NEG_INF = -__builtin_inff();

  // ---- pass 1: row max (lane over ct, shfl over fr, LDS over waves) ----
  float pm[4][4];
#pragma unroll
  for (int rt = 0; rt < 4; ++rt)
#pragma unroll
    for (int r = 0; r < 4; ++r) {
      float m_ = NEG_INF;
#pragma unroll
      for (int ct = 0; ct < 5; ++ct)
        if (vld[ct]) m_ = fmaxf(m_, acc[rt][ct][r] + b1v[ct]);
      pm[rt][r] = m_;
    }
#pragma unroll
  for (int off = 1; off < 16; off <<= 1)
#pragma unroll
    for (int rt = 0; rt < 4; ++rt)
#pragma unroll
      for (int r = 0; r < 4; ++r)
        pm[rt][r] = fmaxf(pm[rt][r], __shfl_xor(pm[rt][r], off, 64));
  if (fr == 0)
#pragma unroll
    for (int rt = 0; rt < 4; ++rt)
#pragma unroll
      for (int r = 0; r < 4; ++r)
        red[wid][rt * 16 + fq * 4 + r] = pm[rt][r];
  __syncthreads();
  if (t < 64) {
    float m_ = red[0][t];
#pragma unroll
    for (int w = 1; w < 8; ++w) m_ = fmaxf(m_, red[w][t]);
    rowM[t] = m_;
  }
  __syncthreads();

  // ---- pass 2: row sum of exp ----
  float rm[4][4];
#pragma unroll
  for (int rt = 0; rt < 4; ++rt)
#pragma unroll
    for (int r = 0; r < 4; ++r) rm[rt][r] = rowM[rt * 16 + fq * 4 + r];
  float ps[4][4];
#pragma unroll
  for (int rt = 0; rt < 4; ++rt)
#pragma unroll
    for (int r = 0; r < 4; ++r) {
      float s = 0.0f;
#pragma unroll
      for (int ct = 0; ct < 5; ++ct)
        if (vld[ct]) s += expf(acc[rt][ct][r] + b1v[ct] - rm[rt][r]);
      ps[rt][r] = s;
    }
#pragma unroll
  for (int off = 1; off < 16; off <<= 1)
#pragma unroll
    for (int rt = 0; rt < 4; ++rt)
#pragma unroll
      for (int r = 0; r < 4; ++r)
        ps[rt][r] += __shfl_xor(ps[rt][r], off, 64);
  if (fr == 0)
#pragma unroll
    for (int rt = 0; rt < 4; ++rt)
#pragma unroll
      for (int r = 0; r < 4; ++r)
        red[wid][rt * 16 + fq * 4 + r] = ps[rt][r];
  __syncthreads();
  if (t < 64) {
    float s = red[0][t];
#pragma unroll
    for (int w = 1; w < 8; ++w) s += red[w][t];
    rowS[t] = s;
    rowL[t] = logf(s);
  }
  __syncthreads();

  // ---- pass 3: probs store + gumbel argmax ----
  float bvv[4][4];
  int bcc[4][4];
#pragma unroll
  for (int rt = 0; rt < 4; ++rt)
#pragma unroll
    for (int r = 0; r < 4; ++r) {
      const int row = rt * 16 + fq * 4 + r;
      const float mr = rm[rt][r];
      const float sr = rowS[row];
      const float lr = rowL[row];
      const uint32_t base = (uint32_t)(m0 + row) * (uint32_t)N_TOTAL;
      float bv = NEG_INF;
      int bc = 0x7FFFFFFF;
#pragma unroll
      for (int ct = 0; ct < 5; ++ct)
        if (vld[ct]) {
          const int col = wid * 80 + ct * 16 + fr;
          const float x = acc[rt][ct][r] + b1v[ct];
          const float e = expf(x - mr);
          probs[(size_t)(m0 + row) * N_TOTAL + col] = e / sr;
          const float sc = jax_gumbel(base + (uint32_t)col) + ((x - mr) - lr);
          if (sc > bv) { bv = sc; bc = col; }
        }
      bvv[rt][r] = bv;
      bcc[rt][r] = bc;
    }
#pragma unroll
  for (int off = 1; off < 16; off <<= 1)
#pragma unroll
    for (int rt = 0; rt < 4; ++rt)
#pragma unroll
      for (int r = 0; r < 4; ++r) {
        const float ov = __shfl_xor(bvv[rt][r], off, 64);
        const int oc = __shfl_xor(bcc[rt][r], off, 64);
        if (ov > bvv[rt][r] || (ov == bvv[rt][r] && oc < bcc[rt][r])) {
          bvv[rt][r] = ov;
          bcc[rt][r] = oc;
        }
      }
  if (fr == 0)
#pragma unroll
    for (int rt = 0; rt < 4; ++rt)
#pragma unroll
      for (int r = 0; r < 4; ++r) {
        avalS[wid][rt * 16 + fq * 4 + r] = bvv[rt][r];
        acolS[wid][rt * 16 + fq * 4 + r] = bcc[rt][r];
      }
  __syncthreads();
  if (t < 64) {
    float bv = avalS[0][t];
    int bc = acolS[0][t];
#pragma unroll
    for (int w = 1; w < 8; ++w) {
      const float ov = avalS[w][t];
      const int oc = acolS[w][t];
      if (ov > bv || (ov == bv && oc < bc)) { bv = ov; bc = oc; }
    }
    actS[t] = bc;
  }
  __syncthreads();

  // ---- pass 4: out1 = relu(W2[action] + b2) + core ----
  const int d0 = t * 2;
  const float2 b2v = *reinterpret_cast<const float2*>(b2 + d0);
  for (int row = 0; row < 64; ++row) {
    const int a = actS[row];
    const float2 wv = *reinterpret_cast<const float2*>(W2 + (size_t)a * D_TOTAL + d0);
    const float2 cv = *reinterpret_cast<const float2*>(A + (size_t)(m0 + row) * D_TOTAL + d0);
    float2 o;
    o.x = fmaxf(wv.x + b2v.x, 0.0f) + cv.x;
    o.y = fmaxf(wv.y + b2v.y, 0.0f) + cv.y;
    *reinterpret_cast<float2*>(out1 + (size_t)(m0 + row) * D_TOTAL + d0) = o;
  }
}

// ---------------------------------------------------------------------------
// Fallback path (only if ws_size too small): f32 GEMM + head kernel
// ---------------------------------------------------------------------------
__global__ __launch_bounds__(256) void gemm_pre(const float* __restrict__ A,
                                                const float* __restrict__ W,
                                                const float* __restrict__ b1,
                                                float* __restrict__ C) {
  __shared__ float As_[16][64];
  __shared__ float Bs_[16][64];
  const int t = threadIdx.x;
  const int tx = t & 15, ty = t >> 4;
  const int m0 = blockIdx.y * 64;
  const int n0 = blockIdx.x * 64;
  const int ar = t >> 2, ac4 = (t & 3) << 2;
  const int bk = t >> 4, bn4 = (t & 15) << 2;
  float acc[4][4] = {};
  for (int k0 = 0; k0 < K_TOTAL; k0 += 16) {
    float4 av = *reinterpret_cast<const float4*>(A + (size_t)(m0 + ar) * K_TOTAL + k0 + ac4);
    As_[ac4 + 0][ar] = av.x;
    As_[ac4 + 1][ar] = av.y;
    As_[ac4 + 2][ar] = av.z;
    As_[ac4 + 3][ar] = av.w;
    float4 bv = make_float4(0.f, 0.f, 0.f, 0.f);
    const int gn = n0 + bn4;
    if (gn < N_TOTAL)
      bv = *reinterpret_cast<const float4*>(W + (size_t)(k0 + bk) * N_TOTAL + gn);
    *reinterpret_cast<float4*>(&Bs_[bk][bn4]) = bv;
    __syncthreads();
#pragma unroll
    for (int kk = 0; kk < 16; ++kk) {
      float4 a = *reinterpret_cast<const float4*>(&As_[kk][ty << 2]);
      float4 b = *reinterpret_cast<const float4*>(&Bs_[kk][tx << 2]);
      const float aa[4] = {a.x, a.y, a.z, a.w};
      const float bb[4] = {b.x, b.y, b.z, b.w};
#pragma unroll
      for (int i = 0; i < 4; ++i)
#pragma unroll
        for (int j = 0; j < 4; ++j)
          acc[i][j] = fmaf(aa[i], bb[j], acc[i][j]);
    }
    __syncthreads();
  }
#pragma unroll
  for (int j = 0; j < 4; ++j) {
    const int n = n0 + (tx << 2) + j;
    if (n < N_TOTAL) {
      const float bj = b1[n];
#pragma unroll
      for (int i = 0; i < 4; ++i) {
        const int m = m0 + (ty << 2) + i;
        C[(size_t)m * N_TOTAL + n] = acc[i][j] + bj;
      }
    }
  }
}

__global__ __launch_bounds__(256) void head_kernel(
    float* __restrict__ pre_probs,
    const float* __restrict__ core,
    const float* __restrict__ W2,
    const float* __restrict__ b2,
    float* __restrict__ out1) {
  const int row = blockIdx.x;
  const int t = threadIdx.x;
  const int lane = t & 63, wid = t >> 6;

  __shared__ float s_max[4];
  __shared__ float s_sum[4];
  __shared__ float s_av[4];
  __shared__ int   s_ai[4];

  float* xrow = pre_probs + (size_t)row * N_TOTAL;
  const int c0 = t, c1 = t + 256, c2 = t + 512;
  const bool v1 = (c1 < N_TOTAL), v2 = (c2 < N_TOTAL);
  const float NEG_INF = -__builtin_inff();

  const float x0v = xrow[c0];
  const float x1v = v1 ? xrow[c1] : NEG_INF;
  const float x2v = v2 ? xrow[c2] : NEG_INF;

  float vmax = fmaxf(x0v, fmaxf(x1v, x2v));
#pragma unroll
  for (int off = 32; off > 0; off >>= 1)
    vmax = fmaxf(vmax, __shfl_xor(vmax, off, 64));
  if (lane == 0) s_max[wid] = vmax;
  __syncthreads();
  const float m = fmaxf(fmaxf(s_max[0], s_max[1]), fmaxf(s_max[2], s_max[3]));

  const float e0 = expf(x0v - m);
  const float e1 = v1 ? expf(x1v - m) : 0.0f;
  const float e2 = v2 ? expf(x2v - m) : 0.0f;
  float vsum = e0 + e1 + e2;
#pragma unroll
  for (int off = 32; off > 0; off >>= 1)
    vsum += __shfl_xor(vsum, off, 64);
  if (lane == 0) s_sum[wid] = vsum;
  __syncthreads();
  const float sum = (s_sum[0] + s_sum[1]) + (s_sum[2] + s_sum[3]);

  const float lse = logf(sum);
  xrow[c0] = e0 / sum;
  if (v1) xrow[c1] = e1 / sum;
  if (v2) xrow[c2] = e2 / sum;

  const uint32_t base = (uint32_t)row * (uint32_t)N_TOTAL;
  float bv = jax_gumbel(base + c0) + ((x0v - m) - lse);
  int bi = c0;
  if (v1) {
    const float s1 = jax_gumbel(base + c1) + ((x1v - m) - lse);
    if (s1 > bv) { bv = s1; bi = c1; }
  }
  if (v2) {
    const float s2 = jax_gumbel(base + c2) + ((x2v - m) - lse);
    if (s2 > bv) { bv = s2; bi = c2; }
  }
#pragma unroll
  for (int off = 32; off > 0; off >>= 1) {
    const float ov = __shfl_xor(bv, off, 64);
    const int oi = __shfl_xor(bi, off, 64);
    if (ov > bv || (ov == bv && oi < bi)) { bv = ov; bi = oi; }
  }
  if (lane == 0) { s_av[wid] = bv; s_ai[wid] = bi; }
  __syncthreads();
  float best = s_av[0]; int action = s_ai[0];
#pragma unroll
  for (int w = 1; w < 4; ++w) {
    if (s_av[w] > best || (s_av[w] == best && s_ai[w] < action)) {
      best = s_av[w]; action = s_ai[w];
    }
  }

  const float* __restrict__ w2row = W2 + (size_t)action * D_TOTAL;
  const float* __restrict__ crow = core + (size_t)row * D_TOTAL;
  float* __restrict__ orow = out1 + (size_t)row * D_TOTAL;
#pragma unroll
  for (int d = t; d < D_TOTAL; d += 256) {
    const float h = w2row[d] + b2[d];
    orow[d] = fmaxf(h, 0.0f) + crow[d];
  }
}

// ---------------------------------------------------------------------------
extern "C" void kernel_launch(void* const* d_in, const int* in_sizes, int n_in,
                              void* d_out, int out_size, void* d_ws, size_t ws_size,
                              hipStream_t stream) {
  const float* core = (const float*)d_in[0];  // [16384,1024]
  const float* W1   = (const float*)d_in[1];  // [1024,572]
  const float* b1   = (const float*)d_in[2];  // [572]
  const float* W2   = (const float*)d_in[3];  // [572,1024]
  const float* b2   = (const float*)d_in[4];  // [1024]

  float* probs = (float*)d_out;                              // [16384,572]
  float* out1  = (float*)d_out + (size_t)M_TOTAL * N_TOTAL;  // [16384,1024]

  const size_t wneed = (size_t)2 * B_PLANE * sizeof(f16);  // 2.62 MB
  if (ws_size >= wneed) {
    f16* Bgr = (f16*)d_ws;
    conv_w_gran<<<(N_PAD * K_TOTAL) / 256, 256, 0, stream>>>(W1, Bgr);
    fused_head<<<M_TOTAL / 64, 512, 0, stream>>>(core, Bgr, b1, W2, b2, probs, out1);
  } else {
    gemm_pre<<<dim3((N_TOTAL + 63) / 64, M_TOTAL / 64), 256, 0, stream>>>(core, W1, b1, probs);
    head_kernel<<<M_TOTAL, 256, 0, stream>>>(probs, core, W2, b2, out1);
  }
}

// Round 11
// 199.462 us; speedup vs baseline: 1.2559x; 1.2559x over previous
//
#include <hip/hip_runtime.h>
#include <hip/hip_fp16.h>
#include <stdint.h>

#define M_TOTAL 16384
#define N_TOTAL 572
#define N_PAD   640
#define K_TOTAL 1024
#define D_TOTAL 1024

typedef _Float16 f16;
typedef __attribute__((ext_vector_type(4))) _Float16 f16x4;
typedef __attribute__((ext_vector_type(8))) _Float16 f16x8;
typedef __attribute__((ext_vector_type(4))) float f32x4;

// B granule array geometry (f16 elements)
#define B_PLANE 655360   // 32 kblk * 40 ct * 4 kseg * 16 fr * 8 e
#define B_KSTEP 20480    // 40*4*16*8 : stride per kblk

// ---------------------------------------------------------------------------
// conv_w_gran: W1 f32 [K,572] -> hi/lo f16 planes in MFMA-granule order:
// elem(p, k, n) at  p*B_PLANE + (((kblk*40 + ct)*4 + kseg)*16 + fr)*8 + e
// where kblk=k>>5, kseg=(k>>3)&3, e=k&7, ct=n>>4, fr=n&15.
// Cols 572..639 zero-filled.  A wave's B-fragment is a contiguous 1KB.
// ---------------------------------------------------------------------------
__global__ __launch_bounds__(256) void conv_w_gran(const float* __restrict__ W,
                                                   f16* __restrict__ Bg) {
  const int idx = blockIdx.x * 256 + threadIdx.x;  // over 640*1024
  const int n = idx % N_PAD;
  const int k = idx / N_PAD;
  const float x = (n < N_TOTAL) ? W[(size_t)k * N_TOTAL + n] : 0.0f;
  const f16 h = (f16)x;
  const f16 l = (f16)(x - (float)h);
  const size_t off = ((((size_t)(k >> 5) * 40 + (n >> 4)) * 4 + ((k >> 3) & 3)) * 16
                      + (n & 15)) * 8 + (k & 7);
  Bg[off] = h;
  Bg[B_PLANE + off] = l;
}

// ---------------------------------------------------------------------------
// JAX threefry2x32, key(42) -> (0,42); partitionable random_bits (32-bit)
// ---------------------------------------------------------------------------
__device__ __forceinline__ float jax_gumbel(uint32_t idx) {
  const uint32_t ks0 = 0u;
  const uint32_t ks1 = 42u;
  const uint32_t ks2 = 0x1BD11BDAu ^ ks0 ^ ks1;
  uint32_t x0 = ks0;
  uint32_t x1 = idx + ks1;
#define TF_ROUND(r) { x0 += x1; x1 = (x1 << (r)) | (x1 >> (32 - (r))); x1 ^= x0; }
  TF_ROUND(13) TF_ROUND(15) TF_ROUND(26) TF_ROUND(6)
  x0 += ks1; x1 += ks2 + 1u;
  TF_ROUND(17) TF_ROUND(29) TF_ROUND(16) TF_ROUND(24)
  x0 += ks2; x1 += ks0 + 2u;
  TF_ROUND(13) TF_ROUND(15) TF_ROUND(26) TF_ROUND(6)
  x0 += ks0; x1 += ks1 + 3u;
  TF_ROUND(17) TF_ROUND(29) TF_ROUND(16) TF_ROUND(24)
  x0 += ks1; x1 += ks2 + 4u;
  TF_ROUND(13) TF_ROUND(15) TF_ROUND(26) TF_ROUND(6)
  x0 += ks2; x1 += ks0 + 5u;
#undef TF_ROUND
  const uint32_t bits = x0 ^ x1;
  union { uint32_t u; float f; } cvt;
  cvt.u = (bits >> 9) | 0x3F800000u;
  const float fl = cvt.f - 1.0f;
  const float TINY = 1.1754943508222875e-38f;
  const float u = fmaxf(TINY, fl * 1.0f + TINY);
  return -logf(-logf(u));
}

// ---------------------------------------------------------------------------
// fused_head: per 64-row block -- GEMM (full 640 cols) + softmax + gumbel
// argmax + W2 gather + relu + residual.  512 thr = 8 waves; wave w owns cols
// [w*80, w*80+80) (5 ct), all 64 rows; acc[4][5].
// K-loop: manual x2 unroll (static indexing). B: two named register sets,
// set refilled right after its MFMAs consume it -> ~1 full step in flight
// (B is L2-resident; ~300cyc latency covered). A: f32->hi/lo f16 in-register,
// double-buffered granule LDS, one barrier per step.
// ---------------------------------------------------------------------------
__global__ __launch_bounds__(512, 2) void fused_head(
    const float* __restrict__ A,
    const f16* __restrict__ Bgr,
    const float* __restrict__ b1,
    const float* __restrict__ W2,
    const float* __restrict__ b2,
    float* __restrict__ probs,
    float* __restrict__ out1) {
  __shared__ __align__(16) f16 AgF[2][2][2048];  // [dbuf][plane][gran*8] 16KB
  __shared__ float red[8][64];
  __shared__ float rowM[64];
  __shared__ float rowS[64];
  __shared__ float rowL[64];
  __shared__ float avalS[8][64];
  __shared__ int   acolS[8][64];
  __shared__ int   actS[64];

  const int t = threadIdx.x;
  const int lane = t & 63, wid = t >> 6;  // wid = col group 0..7
  const int fr = lane & 15, fq = lane >> 4;
  const int m0 = blockIdx.x * 64;

  // ---- A staging: thread t = (granule gi, half hf) ----
  const int gi = t >> 1, hf = t & 1;
  const int aRow = ((gi >> 6) << 4) | (gi & 15);
  const int aK = ((gi >> 4) & 3) * 8 + hf * 4;
  const float* aP = A + (size_t)(m0 + aRow) * K_TOTAL + aK;

  // ---- B base (lane-resolved); ct offset = ct*512 f16, kb offset = kb*B_KSTEP
  const f16* bBase = Bgr + ((((size_t)(wid * 5) * 4 + fq) * 16 + fr) * 8);

  // ---- b1 / validity per ct ----
  float b1v[5];
  bool vld[5];
#pragma unroll
  for (int ct = 0; ct < 5; ++ct) {
    const int col = wid * 80 + ct * 16 + fr;
    vld[ct] = (col < N_TOTAL);
    b1v[ct] = vld[ct] ? b1[col] : 0.0f;
  }

  f32x4 acc[4][5] = {};

  // ---- named prefetch state ----
  float4 rA;
  f16x8 b0h[5], b0l[5], b1h[5], b1l[5];

  auto LOADA = [&](int kb) { rA = *reinterpret_cast<const float4*>(aP + kb * 32); };
  auto WRITEA = [&](int db) {
    const float xv[4] = {rA.x, rA.y, rA.z, rA.w};
    f16x4 hi, lo;
#pragma unroll
    for (int j = 0; j < 4; ++j) {
      const f16 h = (f16)xv[j];
      hi[j] = h;
      lo[j] = (f16)(xv[j] - (float)h);
    }
    *reinterpret_cast<f16x4*>(&AgF[db][0][gi * 8 + hf * 4]) = hi;
    *reinterpret_cast<f16x4*>(&AgF[db][1][gi * 8 + hf * 4]) = lo;
  };
  auto LOADB0 = [&](int kb) {
    const f16* p = bBase + (size_t)kb * B_KSTEP;
#pragma unroll
    for (int ct = 0; ct < 5; ++ct) {
      b0h[ct] = *reinterpret_cast<const f16x8*>(p + ct * 512);
      b0l[ct] = *reinterpret_cast<const f16x8*>(p + B_PLANE + ct * 512);
    }
  };
  auto LOADB1 = [&](int kb) {
    const f16* p = bBase + (size_t)kb * B_KSTEP;
#pragma unroll
    for (int ct = 0; ct < 5; ++ct) {
      b1h[ct] = *reinterpret_cast<const f16x8*>(p + ct * 512);
      b1l[ct] = *reinterpret_cast<const f16x8*>(p + B_PLANE + ct * 512);
    }
  };

  // ---- prologue ----
  LOADB0(0);
  LOADB1(1);
  LOADA(0);
  WRITEA(0);
  __syncthreads();

  // ---- K loop: 16 iterations x 2 half-steps, all indices static ----
  for (int it = 0; it < 16; ++it) {
    const int s0 = it * 2, s1 = it * 2 + 1;

    // ===== even half: compute step s0 from AgF[0], Bset0 =====
    LOADA(s1);  // A data for step s1 (written to AgF[1] at end of this half)
    {
      f16x8 ahh[4], alo[4];
#pragma unroll
      for (int rt = 0; rt < 4; ++rt) {
        ahh[rt] = *reinterpret_cast<const f16x8*>(&AgF[0][0][(rt * 64 + lane) * 8]);
        alo[rt] = *reinterpret_cast<const f16x8*>(&AgF[0][1][(rt * 64 + lane) * 8]);
      }
#pragma unroll
      for (int ct = 0; ct < 5; ++ct)
#pragma unroll
        for (int rt = 0; rt < 4; ++rt) {
          acc[rt][ct] = __builtin_amdgcn_mfma_f32_16x16x32_f16(ahh[rt], b0h[ct], acc[rt][ct], 0, 0, 0);
          acc[rt][ct] = __builtin_amdgcn_mfma_f32_16x16x32_f16(ahh[rt], b0l[ct], acc[rt][ct], 0, 0, 0);
          acc[rt][ct] = __builtin_amdgcn_mfma_f32_16x16x32_f16(alo[rt], b0h[ct], acc[rt][ct], 0, 0, 0);
        }
    }
    if (s0 + 2 < 32) LOADB0(s0 + 2);  // refill set0 right after last use
    WRITEA(1);                        // vmcnt waits for LOADA(s1)
    __syncthreads();

    // ===== odd half: compute step s1 from AgF[1], Bset1 =====
    if (s1 + 1 < 32) LOADA(s1 + 1);  // A data for step s0+2 -> AgF[0]
    {
      f16x8 ahh[4], alo[4];
#pragma unroll
      for (int rt = 0; rt < 4; ++rt) {
        ahh[rt] = *reinterpret_cast<const f16x8*>(&AgF[1][0][(rt * 64 + lane) * 8]);
        alo[rt] = *reinterpret_cast<const f16x8*>(&AgF[1][1][(rt * 64 + lane) * 8]);
      }
#pragma unroll
      for (int ct = 0; ct < 5; ++ct)
#pragma unroll
        for (int rt = 0; rt < 4; ++rt) {
          acc[rt][ct] = __builtin_amdgcn_mfma_f32_16x16x32_f16(ahh[rt], b1h[ct], acc[rt][ct], 0, 0, 0);
          acc[rt][ct] = __builtin_amdgcn_mfma_f32_16x16x32_f16(ahh[rt], b1l[ct], acc[rt][ct], 0, 0, 0);
          acc[rt][ct] = __builtin_amdgcn_mfma_f32_16x16x32_f16(alo[rt], b1h[ct], acc[rt][ct], 0, 0, 0);
        }
    }
    if (s1 + 2 < 32) LOADB1(s1 + 2);  // refill set1 right after last use
    if (s1 + 1 < 32) WRITEA(0);
    __syncthreads();
  }

  const float NEG_INF = -__builtin_inff();

  // ---- pass 1: row max (lane over ct, shfl over fr, LDS over waves) ----
  float pm[4][4];
#pragma unroll
  for (int rt = 0; rt < 4; ++rt)
#pragma unroll
    for (int r = 0; r < 4; ++r) {
      float m_ = NEG_INF;
#pragma unroll
      for (int ct = 0; ct < 5; ++ct)
        if (vld[ct]) m_ = fmaxf(m_, acc[rt][ct][r] + b1v[ct]);
      pm[rt][r] = m_;
    }
#pragma unroll
  for (int off = 1; off < 16; off <<= 1)
#pragma unroll
    for (int rt = 0; rt < 4; ++rt)
#pragma unroll
      for (int r = 0; r < 4; ++r)
        pm[rt][r] = fmaxf(pm[rt][r], __shfl_xor(pm[rt][r], off, 64));
  if (fr == 0)
#pragma unroll
    for (int rt = 0; rt < 4; ++rt)
#pragma unroll
      for (int r = 0; r < 4; ++r)
        red[wid][rt * 16 + fq * 4 + r] = pm[rt][r];
  __syncthreads();
  if (t < 64) {
    float m_ = red[0][t];
#pragma unroll
    for (int w = 1; w < 8; ++w) m_ = fmaxf(m_, red[w][t]);
    rowM[t] = m_;
  }
  __syncthreads();

  // ---- pass 2: row sum of exp ----
  float rm[4][4];
#pragma unroll
  for (int rt = 0; rt < 4; ++rt)
#pragma unroll
    for (int r = 0; r < 4; ++r) rm[rt][r] = rowM[rt * 16 + fq * 4 + r];
  float ps[4][4];
#pragma unroll
  for (int rt = 0; rt < 4; ++rt)
#pragma unroll
    for (int r = 0; r < 4; ++r) {
      float s = 0.0f;
#pragma unroll
      for (int ct = 0; ct < 5; ++ct)
        if (vld[ct]) s += expf(acc[rt][ct][r] + b1v[ct] - rm[rt][r]);
      ps[rt][r] = s;
    }
#pragma unroll
  for (int off = 1; off < 16; off <<= 1)
#pragma unroll
    for (int rt = 0; rt < 4; ++rt)
#pragma unroll
      for (int r = 0; r < 4; ++r)
        ps[rt][r] += __shfl_xor(ps[rt][r], off, 64);
  if (fr == 0)
#pragma unroll
    for (int rt = 0; rt < 4; ++rt)
#pragma unroll
      for (int r = 0; r < 4; ++r)
        red[wid][rt * 16 + fq * 4 + r] = ps[rt][r];
  __syncthreads();
  if (t < 64) {
    float s = red[0][t];
#pragma unroll
    for (int w = 1; w < 8; ++w) s += red[w][t];
    rowS[t] = s;
    rowL[t] = logf(s);
  }
  __syncthreads();

  // ---- pass 3: probs store + gumbel argmax ----
  float bvv[4][4];
  int bcc[4][4];
#pragma unroll
  for (int rt = 0; rt < 4; ++rt)
#pragma unroll
    for (int r = 0; r < 4; ++r) {
      const int row = rt * 16 + fq * 4 + r;
      const float mr = rm[rt][r];
      const float sr = rowS[row];
      const float lr = rowL[row];
      const uint32_t base = (uint32_t)(m0 + row) * (uint32_t)N_TOTAL;
      float bv = NEG_INF;
      int bc = 0x7FFFFFFF;
#pragma unroll
      for (int ct = 0; ct < 5; ++ct)
        if (vld[ct]) {
          const int col = wid * 80 + ct * 16 + fr;
          const float x = acc[rt][ct][r] + b1v[ct];
          const float e = expf(x - mr);
          probs[(size_t)(m0 + row) * N_TOTAL + col] = e / sr;
          const float sc = jax_gumbel(base + (uint32_t)col) + ((x - mr) - lr);
          if (sc > bv) { bv = sc; bc = col; }
        }
      bvv[rt][r] = bv;
      bcc[rt][r] = bc;
    }
#pragma unroll
  for (int off = 1; off < 16; off <<= 1)
#pragma unroll
    for (int rt = 0; rt < 4; ++rt)
#pragma unroll
      for (int r = 0; r < 4; ++r) {
        const float ov = __shfl_xor(bvv[rt][r], off, 64);
        const int oc = __shfl_xor(bcc[rt][r], off, 64);
        if (ov > bvv[rt][r] || (ov == bvv[rt][r] && oc < bcc[rt][r])) {
          bvv[rt][r] = ov;
          bcc[rt][r] = oc;
        }
      }
  if (fr == 0)
#pragma unroll
    for (int rt = 0; rt < 4; ++rt)
#pragma unroll
      for (int r = 0; r < 4; ++r) {
        avalS[wid][rt * 16 + fq * 4 + r] = bvv[rt][r];
        acolS[wid][rt * 16 + fq * 4 + r] = bcc[rt][r];
      }
  __syncthreads();
  if (t < 64) {
    float bv = avalS[0][t];
    int bc = acolS[0][t];
#pragma unroll
    for (int w = 1; w < 8; ++w) {
      const float ov = avalS[w][t];
      const int oc = acolS[w][t];
      if (ov > bv || (ov == bv && oc < bc)) { bv = ov; bc = oc; }
    }
    actS[t] = bc;
  }
  __syncthreads();

  // ---- pass 4: out1 = relu(W2[action] + b2) + core ----
  const int d0 = t * 2;
  const float2 b2v = *reinterpret_cast<const float2*>(b2 + d0);
  for (int row = 0; row < 64; ++row) {
    const int a = actS[row];
    const float2 wv = *reinterpret_cast<const float2*>(W2 + (size_t)a * D_TOTAL + d0);
    const float2 cv = *reinterpret_cast<const float2*>(A + (size_t)(m0 + row) * D_TOTAL + d0);
    float2 o;
    o.x = fmaxf(wv.x + b2v.x, 0.0f) + cv.x;
    o.y = fmaxf(wv.y + b2v.y, 0.0f) + cv.y;
    *reinterpret_cast<float2*>(out1 + (size_t)(m0 + row) * D_TOTAL + d0) = o;
  }
}

// ---------------------------------------------------------------------------
// Fallback path (only if ws_size too small): f32 GEMM + head kernel
// ---------------------------------------------------------------------------
__global__ __launch_bounds__(256) void gemm_pre(const float* __restrict__ A,
                                                const float* __restrict__ W,
                                                const float* __restrict__ b1,
                                                float* __restrict__ C) {
  __shared__ float As_[16][64];
  __shared__ float Bs_[16][64];
  const int t = threadIdx.x;
  const int tx = t & 15, ty = t >> 4;
  const int m0 = blockIdx.y * 64;
  const int n0 = blockIdx.x * 64;
  const int ar = t >> 2, ac4 = (t & 3) << 2;
  const int bk = t >> 4, bn4 = (t & 15) << 2;
  float acc[4][4] = {};
  for (int k0 = 0; k0 < K_TOTAL; k0 += 16) {
    float4 av = *reinterpret_cast<const float4*>(A + (size_t)(m0 + ar) * K_TOTAL + k0 + ac4);
    As_[ac4 + 0][ar] = av.x;
    As_[ac4 + 1][ar] = av.y;
    As_[ac4 + 2][ar] = av.z;
    As_[ac4 + 3][ar] = av.w;
    float4 bv = make_float4(0.f, 0.f, 0.f, 0.f);
    const int gn = n0 + bn4;
    if (gn < N_TOTAL)
      bv = *reinterpret_cast<const float4*>(W + (size_t)(k0 + bk) * N_TOTAL + gn);
    *reinterpret_cast<float4*>(&Bs_[bk][bn4]) = bv;
    __syncthreads();
#pragma unroll
    for (int kk = 0; kk < 16; ++kk) {
      float4 a = *reinterpret_cast<const float4*>(&As_[kk][ty << 2]);
      float4 b = *reinterpret_cast<const float4*>(&Bs_[kk][tx << 2]);
      const float aa[4] = {a.x, a.y, a.z, a.w};
      const float bb[4] = {b.x, b.y, b.z, b.w};
#pragma unroll
      for (int i = 0; i < 4; ++i)
#pragma unroll
        for (int j = 0; j < 4; ++j)
          acc[i][j] = fmaf(aa[i], bb[j], acc[i][j]);
    }
    __syncthreads();
  }
#pragma unroll
  for (int j = 0; j < 4; ++j) {
    const int n = n0 + (tx << 2) + j;
    if (n < N_TOTAL) {
      const float bj = b1[n];
#pragma unroll
      for (int i = 0; i < 4; ++i) {
        const int m = m0 + (ty << 2) + i;
        C[(size_t)m * N_TOTAL + n] = acc[i][j] + bj;
      }
    }
  }
}

__global__ __launch_bounds__(256) void head_kernel(
    float* __restrict__ pre_probs,
    const float* __restrict__ core,
    const float* __restrict__ W2,
    const float* __restrict__ b2,
    float* __restrict__ out1) {
  const int row = blockIdx.x;
  const int t = threadIdx.x;
  const int lane = t & 63, wid = t >> 6;

  __shared__ float s_max[4];
  __shared__ float s_sum[4];
  __shared__ float s_av[4];
  __shared__ int   s_ai[4];

  float* xrow = pre_probs + (size_t)row * N_TOTAL;
  const int c0 = t, c1 = t + 256, c2 = t + 512;
  const bool v1 = (c1 < N_TOTAL), v2 = (c2 < N_TOTAL);
  const float NEG_INF = -__builtin_inff();

  const float x0v = xrow[c0];
  const float x1v = v1 ? xrow[c1] : NEG_INF;
  const float x2v = v2 ? xrow[c2] : NEG_INF;

  float vmax = fmaxf(x0v, fmaxf(x1v, x2v));
#pragma unroll
  for (int off = 32; off > 0; off >>= 1)
    vmax = fmaxf(vmax, __shfl_xor(vmax, off, 64));
  if (lane == 0) s_max[wid] = vmax;
  __syncthreads();
  const float m = fmaxf(fmaxf(s_max[0], s_max[1]), fmaxf(s_max[2], s_max[3]));

  const float e0 = expf(x0v - m);
  const float e1 = v1 ? expf(x1v - m) : 0.0f;
  const float e2 = v2 ? expf(x2v - m) : 0.0f;
  float vsum = e0 + e1 + e2;
#pragma unroll
  for (int off = 32; off > 0; off >>= 1)
    vsum += __shfl_xor(vsum, off, 64);
  if (lane == 0) s_sum[wid] = vsum;
  __syncthreads();
  const float sum = (s_sum[0] + s_sum[1]) + (s_sum[2] + s_sum[3]);

  const float lse = logf(sum);
  xrow[c0] = e0 / sum;
  if (v1) xrow[c1] = e1 / sum;
  if (v2) xrow[c2] = e2 / sum;

  const uint32_t base = (uint32_t)row * (uint32_t)N_TOTAL;
  float bv = jax_gumbel(base + c0) + ((x0v - m) - lse);
  int bi = c0;
  if (v1) {
    const float s1 = jax_gumbel(base + c1) + ((x1v - m) - lse);
    if (s1 > bv) { bv = s1; bi = c1; }
  }
  if (v2) {
    const float s2 = jax_gumbel(base + c2) + ((x2v - m) - lse);
    if (s2 > bv) { bv = s2; bi = c2; }
  }
#pragma unroll
  for (int off = 32; off > 0; off >>= 1) {
    const float ov = __shfl_xor(bv, off, 64);
    const int oi = __shfl_xor(bi, off, 64);
    if (ov > bv || (ov == bv && oi < bi)) { bv = ov; bi = oi; }
  }
  if (lane == 0) { s_av[wid] = bv; s_ai[wid] = bi; }
  __syncthreads();
  float best = s_av[0]; int action = s_ai[0];
#pragma unroll
  for (int w = 1; w < 4; ++w) {
    if (s_av[w] > best || (s_av[w] == best && s_ai[w] < action)) {
      best = s_av[w]; action = s_ai[w];
    }
  }

  const float* __restrict__ w2row = W2 + (size_t)action * D_TOTAL;
  const float* __restrict__ crow = core + (size_t)row * D_TOTAL;
  float* __restrict__ orow = out1 + (size_t)row * D_TOTAL;
#pragma unroll
  for (int d = t; d < D_TOTAL; d += 256) {
    const float h = w2row[d] + b2[d];
    orow[d] = fmaxf(h, 0.0f) + crow[d];
  }
}

// ---------------------------------------------------------------------------
extern "C" void kernel_launch(void* const* d_in, const int* in_sizes, int n_in,
                              void* d_out, int out_size, void* d_ws, size_t ws_size,
                              hipStream_t stream) {
  const float* core = (const float*)d_in[0];  // [16384,1024]
  const float* W1   = (const float*)d_in[1];  // [1024,572]
  const float* b1   = (const float*)d_in[2];  // [572]
  const float* W2   = (const float*)d_in[3];  // [572,1024]
  const float* b2   = (const float*)d_in[4];  // [1024]

  float* probs = (float*)d_out;                              // [16384,572]
  float* out1  = (float*)d_out + (size_t)M_TOTAL * N_TOTAL;  // [16384,1024]

  const size_t wneed = (size_t)2 * B_PLANE * sizeof(f16);  // 2.62 MB
  if (ws_size >= wneed) {
    f16* Bgr = (f16*)d_ws;
    conv_w_gran<<<(N_PAD * K_TOTAL) / 256, 256, 0, stream>>>(W1, Bgr);
    fused_head<<<M_TOTAL / 64, 512, 0, stream>>>(core, Bgr, b1, W2, b2, probs, out1);
  } else {
    gemm_pre<<<dim3((N_TOTAL + 63) / 64, M_TOTAL / 64), 256, 0, stream>>>(core, W1, b1, probs);
    head_kernel<<<M_TOTAL, 256, 0, stream>>>(probs, core, W2, b2, out1);
  }
}